// Round 1
// baseline (393.284 us; speedup 1.0000x reference)
//
#include <hip/hip_runtime.h>
#include <hip/hip_bf16.h>

#define NN 2048
#define BB 8
#define FD 256
#define NEG_SLOPE 0.2f
#define EPSV 1e-7f

typedef __bf16 bf16x8 __attribute__((ext_vector_type(8)));
typedef __bf16 bf16x4 __attribute__((ext_vector_type(4)));
typedef float f32x4 __attribute__((ext_vector_type(4)));

// K1: WT[o][f] = bf16(W[f][o]); zero den
__global__ __launch_bounds__(256) void k1_prep(const float* __restrict__ W,
                                               __bf16* __restrict__ WT,
                                               float* __restrict__ den) {
    int idx = blockIdx.x * 256 + threadIdx.x;
    if (idx < FD * FD) {
        int o = idx >> 8, f = idx & 255;
        WT[idx] = (__bf16)W[f * FD + o];
    }
    if (idx < BB * NN) den[idx] = 0.f;
}

// K2: Wh = x @ W  (bf16 MFMA, fp32 out). wave = 16 rows x 128 cols.
__global__ __launch_bounds__(256) void k2_whgemm(const float* __restrict__ x,
                                                 const __bf16* __restrict__ WT,
                                                 float* __restrict__ Wh) {
    const int wave = threadIdx.x >> 6;
    const int lane = threadIdx.x & 63;
    const int row0 = blockIdx.x * 32 + (wave >> 1) * 16;
    const int ohalf = (wave & 1) * 128;
    const int m = lane & 15;
    const int quad = lane >> 4;
    const int row = row0 + m;
    const float* xrow = x + (size_t)row * FD + quad * 8;

    f32x4 acc[8];
#pragma unroll
    for (int n = 0; n < 8; ++n) acc[n] = (f32x4){0.f, 0.f, 0.f, 0.f};

    for (int k0 = 0; k0 < FD; k0 += 32) {
        float4 xa = *(const float4*)(xrow + k0);
        float4 xb = *(const float4*)(xrow + k0 + 4);
        bf16x8 af;
        af[0] = (__bf16)xa.x; af[1] = (__bf16)xa.y; af[2] = (__bf16)xa.z; af[3] = (__bf16)xa.w;
        af[4] = (__bf16)xb.x; af[5] = (__bf16)xb.y; af[6] = (__bf16)xb.z; af[7] = (__bf16)xb.w;
#pragma unroll
        for (int n = 0; n < 8; ++n) {
            int o = ohalf + n * 16 + m;
            bf16x8 bf = *(const bf16x8*)(WT + o * FD + k0 + quad * 8);
            acc[n] = __builtin_amdgcn_mfma_f32_16x16x32_bf16(af, bf, acc[n], 0, 0, 0);
        }
    }
#pragma unroll
    for (int n = 0; n < 8; ++n) {
        int o = ohalf + n * 16 + m;
#pragma unroll
        for (int r = 0; r < 4; ++r) {
            Wh[(size_t)(row0 + quad * 4 + r) * FD + o] = acc[n][r];
        }
    }
}

// K3: s_src[row] = Wh[row]·a_w[0:256], s_dst[row] = Wh[row]·a_w[256:512]
__global__ __launch_bounds__(256) void k3_scores(const float* __restrict__ Wh,
                                                 const float* __restrict__ a_w,
                                                 float* __restrict__ s_src,
                                                 float* __restrict__ s_dst) {
    int wave = threadIdx.x >> 6, lane = threadIdx.x & 63;
    int row = blockIdx.x * 4 + wave;
    float4 wv = *(const float4*)(Wh + (size_t)row * FD + lane * 4);
    float4 a0 = *(const float4*)(a_w + lane * 4);
    float4 a1 = *(const float4*)(a_w + FD + lane * 4);
    float d0 = wv.x * a0.x + wv.y * a0.y + wv.z * a0.z + wv.w * a0.w;
    float d1 = wv.x * a1.x + wv.y * a1.y + wv.z * a1.z + wv.w * a1.w;
#pragma unroll
    for (int off = 32; off; off >>= 1) {
        d0 += __shfl_down(d0, off, 64);
        d1 += __shfl_down(d1, off, 64);
    }
    if (lane == 0) { s_src[row] = d0; s_dst[row] = d1; }
}

// K4: den[b][j] = sum_i A[b][i][j] * exp(lrelu(s_src[i]+s_dst[j]+ab))
__global__ __launch_bounds__(256) void k4_den(const float* __restrict__ A,
                                              const float* __restrict__ s_src,
                                              const float* __restrict__ s_dst,
                                              const float* __restrict__ a_bp,
                                              float* __restrict__ den) {
    const int b = blockIdx.z;
    const int j = blockIdx.x * 1024 + threadIdx.x * 4;
    const int i0 = blockIdx.y * 64;
    const float ab = a_bp[0];
    __shared__ float ss[64];
    if (threadIdx.x < 64) ss[threadIdx.x] = s_src[b * NN + i0 + threadIdx.x] + ab;
    __syncthreads();
    float4 sd = *(const float4*)(s_dst + b * NN + j);
    float ax = 0.f, ay = 0.f, az = 0.f, aw = 0.f;
    const float* Ap = A + ((size_t)b * NN + i0) * NN + j;
#pragma unroll 4
    for (int i = 0; i < 64; ++i) {
        float4 a = *(const float4*)(Ap + (size_t)i * NN);
        float si = ss[i];
        float e0 = si + sd.x; e0 = e0 > 0.f ? e0 : NEG_SLOPE * e0;
        float e1 = si + sd.y; e1 = e1 > 0.f ? e1 : NEG_SLOPE * e1;
        float e2 = si + sd.z; e2 = e2 > 0.f ? e2 : NEG_SLOPE * e2;
        float e3 = si + sd.w; e3 = e3 > 0.f ? e3 : NEG_SLOPE * e3;
        ax += a.x * __expf(e0);
        ay += a.y * __expf(e1);
        az += a.z * __expf(e2);
        aw += a.w * __expf(e3);
    }
    atomicAdd(&den[b * NN + j + 0], ax);
    atomicAdd(&den[b * NN + j + 1], ay);
    atomicAdd(&den[b * NN + j + 2], az);
    atomicAdd(&den[b * NN + j + 3], aw);
}

// K5: WhT[b][o][j] = bf16( Wh[b][j][o] / (den[b][j]+eps) )
__global__ __launch_bounds__(256) void k5_wht(const float* __restrict__ Wh,
                                              const float* __restrict__ den,
                                              __bf16* __restrict__ WhT) {
    const int b = blockIdx.z;
    const int j0 = blockIdx.x * 64;
    const int o0 = blockIdx.y * 64;
    __shared__ float tile[64][65];
    __shared__ float invd[64];
    if (threadIdx.x < 64) invd[threadIdx.x] = 1.f / (den[b * NN + j0 + threadIdx.x] + EPSV);
    __syncthreads();
    int jr = threadIdx.x >> 4, oc = (threadIdx.x & 15) * 4;
#pragma unroll
    for (int p = 0; p < 4; ++p) {
        int j = jr + p * 16;
        float4 v = *(const float4*)(Wh + (size_t)(b * NN + j0 + j) * FD + o0 + oc);
        float s = invd[j];
        tile[j][oc + 0] = v.x * s;
        tile[j][oc + 1] = v.y * s;
        tile[j][oc + 2] = v.z * s;
        tile[j][oc + 3] = v.w * s;
    }
    __syncthreads();
    int ow = threadIdx.x >> 4, jc = (threadIdx.x & 15) * 4;
#pragma unroll
    for (int p = 0; p < 4; ++p) {
        int o = ow + p * 16;
        bf16x4 w;
        w[0] = (__bf16)tile[jc + 0][o];
        w[1] = (__bf16)tile[jc + 1][o];
        w[2] = (__bf16)tile[jc + 2][o];
        w[3] = (__bf16)tile[jc + 3][o];
        *(bf16x4*)(WhT + (size_t)(b * FD + o0 + o) * NN + j0 + jc) = w;
    }
}

// K6: out[b][i][o] = sum_j (A*exp(lrelu(e)))[i][j] * WhT'[o][j]  (fused, bf16 MFMA)
__global__ __launch_bounds__(256) void k6_out(const float* __restrict__ A,
                                              const __bf16* __restrict__ WhT,
                                              const float* __restrict__ s_src,
                                              const float* __restrict__ s_dst,
                                              const float* __restrict__ a_bp,
                                              float* __restrict__ out) {
    const int b = blockIdx.y;
    const int wave = threadIdx.x >> 6;
    const int lane = threadIdx.x & 63;
    const int i0 = blockIdx.x * 32 + (wave >> 1) * 16;
    const int ohalf = (wave & 1) * 128;
    const int m = lane & 15;
    const int quad = lane >> 4;
    const int row = i0 + m;
    const float ab = a_bp[0];
    const float ssr = s_src[b * NN + row] + ab;
    const float* Arow = A + ((size_t)b * NN + row) * NN + quad * 8;
    const float* sdp = s_dst + b * NN + quad * 8;
    const __bf16* Bbase = WhT + (size_t)(b * FD + ohalf + m) * NN + quad * 8;

    f32x4 acc[8];
#pragma unroll
    for (int n = 0; n < 8; ++n) acc[n] = (f32x4){0.f, 0.f, 0.f, 0.f};

    for (int j0 = 0; j0 < NN; j0 += 32) {
        float4 a0 = *(const float4*)(Arow + j0);
        float4 a1 = *(const float4*)(Arow + j0 + 4);
        float4 s0 = *(const float4*)(sdp + j0);
        float4 s1 = *(const float4*)(sdp + j0 + 4);
        bf16x8 af;
        float e;
        e = ssr + s0.x; e = e > 0.f ? e : NEG_SLOPE * e; af[0] = (__bf16)(a0.x * __expf(e));
        e = ssr + s0.y; e = e > 0.f ? e : NEG_SLOPE * e; af[1] = (__bf16)(a0.y * __expf(e));
        e = ssr + s0.z; e = e > 0.f ? e : NEG_SLOPE * e; af[2] = (__bf16)(a0.z * __expf(e));
        e = ssr + s0.w; e = e > 0.f ? e : NEG_SLOPE * e; af[3] = (__bf16)(a0.w * __expf(e));
        e = ssr + s1.x; e = e > 0.f ? e : NEG_SLOPE * e; af[4] = (__bf16)(a1.x * __expf(e));
        e = ssr + s1.y; e = e > 0.f ? e : NEG_SLOPE * e; af[5] = (__bf16)(a1.y * __expf(e));
        e = ssr + s1.z; e = e > 0.f ? e : NEG_SLOPE * e; af[6] = (__bf16)(a1.z * __expf(e));
        e = ssr + s1.w; e = e > 0.f ? e : NEG_SLOPE * e; af[7] = (__bf16)(a1.w * __expf(e));
#pragma unroll
        for (int n = 0; n < 8; ++n) {
            bf16x8 bf = *(const bf16x8*)(Bbase + (size_t)(n * 16) * NN + j0);
            acc[n] = __builtin_amdgcn_mfma_f32_16x16x32_bf16(af, bf, acc[n], 0, 0, 0);
        }
    }
#pragma unroll
    for (int n = 0; n < 8; ++n) {
        int o = ohalf + n * 16 + m;
#pragma unroll
        for (int r = 0; r < 4; ++r) {
            out[((size_t)b * NN + i0 + quad * 4 + r) * FD + o] = acc[n][r];
        }
    }
}

extern "C" void kernel_launch(void* const* d_in, const int* in_sizes, int n_in,
                              void* d_out, int out_size, void* d_ws, size_t ws_size,
                              hipStream_t stream) {
    const float* A   = (const float*)d_in[0];
    const float* x   = (const float*)d_in[1];
    const float* W   = (const float*)d_in[2];
    const float* a_w = (const float*)d_in[3];
    const float* a_b = (const float*)d_in[4];
    float* out = (float*)d_out;

    char* ws = (char*)d_ws;
    __bf16* WT   = (__bf16*)ws;                                   // 256*256*2      = 131072 B
    float*  Wh   = (float*)(ws + 131072);                         // 16384*256*4    = 16777216 B
    __bf16* WhT  = (__bf16*)(ws + 131072 + 16777216);             // 8*256*2048*2   = 8388608 B
    float*  s_src = (float*)(ws + 131072 + 16777216 + 8388608);   // 16384*4
    float*  s_dst = s_src + 16384;
    float*  den   = s_dst + 16384;

    k1_prep<<<256, 256, 0, stream>>>(W, WT, den);
    k2_whgemm<<<512, 256, 0, stream>>>(x, WT, Wh);
    k3_scores<<<4096, 256, 0, stream>>>(Wh, a_w, s_src, s_dst);
    k4_den<<<dim3(2, 32, 8), 256, 0, stream>>>(A, s_src, s_dst, a_b, den);
    k5_wht<<<dim3(32, 4, 8), 256, 0, stream>>>(Wh, den, WhT);
    k6_out<<<dim3(64, 8), 256, 0, stream>>>(A, WhT, s_src, s_dst, a_b, out);
}